// Round 5
// baseline (215.630 us; speedup 1.0000x reference)
//
#include <hip/hip_runtime.h>
#include <hip/hip_bf16.h>
#include <cstdint>
#include <cstddef>

constexpr int Bn = 8;
constexpr int Nn = 2048;
constexpr int Dn = 128;

typedef __bf16 bf16x8 __attribute__((ext_vector_type(8)));
typedef float f32x4 __attribute__((ext_vector_type(4)));

#define AS1 __attribute__((address_space(1)))
#define AS3 __attribute__((address_space(3)))

static __device__ __forceinline__ void gl_lds16(const void* g, void* l) {
  __builtin_amdgcn_global_load_lds((AS1 const void*)g, (AS3 void*)l, 16, 0, 0);
}

// -----------------------------------------------------------------------------
// Kernel 1: h = x@W (fp32), s1 = h@a1, s2 = h@a2, hT bf16 [B][D][N].
// Fused: pack adj -> bitmask via __ballot (tail loop, overlaps other blocks).
// 512 blocks x 256 thr; 32 rows/block; thread tile 2 rows x 8 cols.
// -----------------------------------------------------------------------------
__global__ __launch_bounds__(256) void gat_k1(
    const float* __restrict__ x, const float* __restrict__ W,
    const float* __restrict__ a_vec, const int* __restrict__ adj,
    __bf16* __restrict__ hT, float* __restrict__ s1, float* __restrict__ s2,
    unsigned long long* __restrict__ mask64) {
  __shared__ __align__(16) float Wl[64 * 144];
  __shared__ __align__(16) float xL[32 * 132];

  const int t = threadIdx.x;
  const int r0 = blockIdx.x * 32;
  const int b = r0 >> 11;
  const int n0 = r0 & (Nn - 1);
  const int rp = (t >> 4) << 1;
  const int c0 = (t & 15) << 3;
  const int c0p = c0 + ((c0 >> 5) << 2);

  float acc[2][8];
#pragma unroll
  for (int r = 0; r < 2; ++r)
#pragma unroll
    for (int c = 0; c < 8; ++c) acc[r][c] = 0.f;

#pragma unroll
  for (int it = 0; it < 4; ++it) {
    int idx = t + (it << 8);
    int rr = idx >> 5, kc = (idx & 31) << 2;
    *(float4*)(xL + rr * 132 + kc) = *(const float4*)(x + (size_t)(r0 + rr) * Dn + kc);
  }

  for (int ph = 0; ph < 2; ++ph) {
    if (ph) __syncthreads();
#pragma unroll
    for (int it = 0; it < 8; ++it) {
      int idx = t + (it << 8);
      int kk = idx >> 5, c4 = (idx & 31) << 2;
      int dsto = kk * 144 + c4 + ((c4 >> 5) << 2);
      *(float4*)(Wl + dsto) = *(const float4*)(W + (size_t)((ph << 6) + kk) * Dn + c4);
    }
    __syncthreads();
    const float* xrow = xL + rp * 132 + (ph << 6);
    for (int k = 0; k < 64; ++k) {
      float xa0 = xrow[k];
      float xa1 = xrow[132 + k];
      float4 w0 = *(const float4*)(Wl + k * 144 + c0p);
      float4 w1 = *(const float4*)(Wl + k * 144 + c0p + 4);
      float ws[8] = {w0.x, w0.y, w0.z, w0.w, w1.x, w1.y, w1.z, w1.w};
#pragma unroll
      for (int c = 0; c < 8; ++c) {
        acc[0][c] = fmaf(xa0, ws[c], acc[0][c]);
        acc[1][c] = fmaf(xa1, ws[c], acc[1][c]);
      }
    }
  }

  float q1[2] = {0.f, 0.f}, q2[2] = {0.f, 0.f};
#pragma unroll
  for (int c = 0; c < 8; ++c) {
    float a1c = a_vec[c0 + c];
    float a2c = a_vec[Dn + c0 + c];
    q1[0] = fmaf(acc[0][c], a1c, q1[0]);
    q1[1] = fmaf(acc[1][c], a1c, q1[1]);
    q2[0] = fmaf(acc[0][c], a2c, q2[0]);
    q2[1] = fmaf(acc[1][c], a2c, q2[1]);
  }
#pragma unroll
  for (int d = 1; d < 16; d <<= 1) {
    q1[0] += __shfl_xor(q1[0], d);
    q1[1] += __shfl_xor(q1[1], d);
    q2[0] += __shfl_xor(q2[0], d);
    q2[1] += __shfl_xor(q2[1], d);
  }
  if ((t & 15) == 0) {
    s1[b * Nn + n0 + rp] = q1[0];
    s1[b * Nn + n0 + rp + 1] = q1[1];
    s2[b * Nn + n0 + rp] = q2[0];
    s2[b * Nn + n0 + rp + 1] = q2[1];
  }

#pragma unroll
  for (int c = 0; c < 8; ++c) {
    union { __bf16 h[2]; uint32_t u; } pk;
    pk.h[0] = (__bf16)acc[0][c];
    pk.h[1] = (__bf16)acc[1][c];
    *(uint32_t*)(hT + (size_t)(b * Dn + c0 + c) * Nn + n0 + rp) = pk.u;
  }

  // fused adj pack: this block covers ints [blockIdx*8192, +8192)
  {
    const size_t base = (size_t)blockIdx.x * 8192;
#pragma unroll 4
    for (int it = 0; it < 32; ++it) {
      size_t g = base + (it << 8) + t;
      int v = adj[g];
      unsigned long long bal = __ballot(v > 0);
      if ((t & 63) == 0) mask64[g >> 6] = bal;
    }
  }
}

// -----------------------------------------------------------------------------
// Kernel 2a: softmax denominators. invl[b][i] = 1 / sum_j bit*exp(lrelu(si+sj)).
// 512 blocks x 256 thr; 32 rows/block, 8 thr/row.
// -----------------------------------------------------------------------------
__global__ __launch_bounds__(256) void gat_k2a(
    const uint32_t* __restrict__ mask, const float* __restrict__ s1,
    const float* __restrict__ s2, float* __restrict__ invl_g) {
  __shared__ __align__(16) float sj[Nn];
  const int t = threadIdx.x;
  const int b = blockIdx.x & 7;
  const int i0 = (blockIdx.x >> 3) << 5;
#pragma unroll
  for (int it = 0; it < 2; ++it) {
    int idx = (t + (it << 8)) << 2;
    *(float4*)(sj + idx) = *(const float4*)(s2 + b * Nn + idx);
  }
  __syncthreads();

  const int ii = t >> 3, sub = t & 7;
  const int i = i0 + ii;
  const uint32_t* __restrict__ mrow = mask + ((size_t)i << 6);
  const float si = s1[b * Nn + i];
  const int bsh = sub << 2;

  float l = 0.f;
  for (int cc = 0; cc < 64; ++cc) {
    uint32_t mw = mrow[cc];
    float4 sv = *(const float4*)(sj + (cc << 5) + bsh);
    float e;
    e = si + sv.x; e = fmaxf(e, 0.2f * e); l += ((mw >> (bsh + 0)) & 1u) ? __expf(e) : 0.f;
    e = si + sv.y; e = fmaxf(e, 0.2f * e); l += ((mw >> (bsh + 1)) & 1u) ? __expf(e) : 0.f;
    e = si + sv.z; e = fmaxf(e, 0.2f * e); l += ((mw >> (bsh + 2)) & 1u) ? __expf(e) : 0.f;
    e = si + sv.w; e = fmaxf(e, 0.2f * e); l += ((mw >> (bsh + 3)) & 1u) ? __expf(e) : 0.f;
  }
  l += __shfl_xor(l, 1);
  l += __shfl_xor(l, 2);
  l += __shfl_xor(l, 4);
  if (sub == 0) invl_g[b * Nn + i] = 1.f / l;
}

// -----------------------------------------------------------------------------
// Kernel 2bc: block-specialized. Blocks [0,512): out-GEMM via MFMA (no global
// stores in K-loop). Blocks [512,1536): barrier-free alpha writers (NT stores).
// 512 threads each.
// -----------------------------------------------------------------------------
__global__ __launch_bounds__(512) void gat_k2bc(
    const uint32_t* __restrict__ mask, const __bf16* __restrict__ hT,
    const float* __restrict__ s1, const float* __restrict__ s2,
    const float* __restrict__ invl_g,
    float* __restrict__ out, float* __restrict__ alpha) {
  __shared__ __align__(16) float sj[Nn];            // 8 KB
  __shared__ float siv[32], ilv[32];
  __shared__ __align__(16) __bf16 Pl[2][32 * 72];   // 9 KB
  __shared__ __align__(16) __bf16 hl[2][128 * 64];  // 32 KB, swizzled

  const int t = threadIdx.x;

  if (blockIdx.x >= 512) {
    // ---------------- alpha writer: 16 rows, pure streaming ----------------
    const int a = blockIdx.x - 512;
    const int b = a & 7;
    const int i0 = (a >> 3) << 4;
    const int j0 = t << 2;
    const float4 sv = *(const float4*)(s2 + b * Nn + j0);
    const int wi = t >> 3, bsh = (t & 7) << 2;
    float e0 = sv.x, e1 = sv.y, e2 = sv.z, e3 = sv.w;  // sj components
    float* __restrict__ arow = alpha + (((size_t)(b * Nn + i0)) << 11) + j0;
#pragma unroll 2
    for (int r = 0; r < 16; ++r) {
      const int i = i0 + r;
      const float si = s1[b * Nn + i];
      const float il = invl_g[b * Nn + i];
      const uint32_t mw = mask[((size_t)i << 6) + wi];
      float a0 = si + e0; a0 = fmaxf(a0, 0.2f * a0);
      float a1 = si + e1; a1 = fmaxf(a1, 0.2f * a1);
      float a2 = si + e2; a2 = fmaxf(a2, 0.2f * a2);
      float a3 = si + e3; a3 = fmaxf(a3, 0.2f * a3);
      f32x4 av;
      av.x = ((mw >> (bsh + 0)) & 1u) ? __expf(a0) * il : 0.f;
      av.y = ((mw >> (bsh + 1)) & 1u) ? __expf(a1) * il : 0.f;
      av.z = ((mw >> (bsh + 2)) & 1u) ? __expf(a2) * il : 0.f;
      av.w = ((mw >> (bsh + 3)) & 1u) ? __expf(a3) * il : 0.f;
      __builtin_nontemporal_store(av, (f32x4*)(arow + ((size_t)r << 11)));
    }
    return;
  }

  // ---------------- out-GEMM block ----------------
  const int b = blockIdx.x & 7;
  const int i0 = (blockIdx.x >> 3) << 5;
  const int w = t >> 6, lane = t & 63;
  const int ii = t >> 4, sub = t & 15;
  const int lrow = lane >> 3, ccs = lane & 7;
  const __bf16* __restrict__ hTb = hT + (size_t)b * Dn * Nn;

  // prologue: prefetch j-tile 0 into hl[0]
#pragma unroll
  for (int inst = 0; inst < 2; ++inst) {
    gl_lds16(hTb + (size_t)((w << 4) + (inst << 3) + lrow) * Nn + ((ccs ^ lrow) << 3),
             &hl[0][((w << 4) + (inst << 3)) << 6]);
  }

  *(float4*)(sj + (t << 2)) = *(const float4*)(s2 + b * Nn + (t << 2));
  if (t < 32) {
    siv[t] = s1[b * Nn + i0 + t];
    ilv[t] = invl_g[b * Nn + i0 + t];
  }
  __syncthreads();

  const int i = i0 + ii;
  const uint32_t* __restrict__ mrow = mask + ((size_t)i << 6);
  const float si = siv[ii];
  const float il = ilv[ii];
  const int wofs = sub >> 3;
  const int bsh = (sub & 7) << 2;

  const int iw = (w & 1) << 4;
  const int nd0 = (w >> 1) << 5;
  const int q16 = lane >> 4, m16 = lane & 15;
  f32x4 acc0 = {0.f, 0.f, 0.f, 0.f}, acc1 = {0.f, 0.f, 0.f, 0.f};

  for (int jt = 0; jt < 32; ++jt) {
    const int buf = jt & 1;
    const int j0 = jt << 6;
    {
      int j = j0 + (sub << 2);
      uint32_t mw = mrow[(j0 >> 5) + wofs];
      float4 sv = *(const float4*)(sj + j);
      float e0 = si + sv.x; e0 = fmaxf(e0, 0.2f * e0);
      float e1 = si + sv.y; e1 = fmaxf(e1, 0.2f * e1);
      float e2 = si + sv.z; e2 = fmaxf(e2, 0.2f * e2);
      float e3 = si + sv.w; e3 = fmaxf(e3, 0.2f * e3);
      float a0 = ((mw >> (bsh + 0)) & 1u) ? __expf(e0) * il : 0.f;
      float a1 = ((mw >> (bsh + 1)) & 1u) ? __expf(e1) * il : 0.f;
      float a2 = ((mw >> (bsh + 2)) & 1u) ? __expf(e2) * il : 0.f;
      float a3 = ((mw >> (bsh + 3)) & 1u) ? __expf(e3) * il : 0.f;
      union { __bf16 h[4]; uint2 u; } pk;
      pk.h[0] = (__bf16)a0; pk.h[1] = (__bf16)a1;
      pk.h[2] = (__bf16)a2; pk.h[3] = (__bf16)a3;
      *(uint2*)(&Pl[buf][ii * 72 + (sub << 2)]) = pk.u;
    }
    __syncthreads();  // hl[buf] DMA drained; Pl[buf] visible; prev MFMA reads done
    if (jt < 31) {
      int jn = j0 + 64;
#pragma unroll
      for (int inst = 0; inst < 2; ++inst) {
        gl_lds16(hTb + (size_t)((w << 4) + (inst << 3) + lrow) * Nn + jn + ((ccs ^ lrow) << 3),
                 &hl[buf ^ 1][((w << 4) + (inst << 3)) << 6]);
      }
    }
#pragma unroll
    for (int ks = 0; ks < 2; ++ks) {
      bf16x8 af = *(const bf16x8*)(&Pl[buf][(iw + m16) * 72 + (ks << 5) + (q16 << 3)]);
      {
        int d = nd0 + m16;
        int phys = ((ks << 2) + q16) ^ (d & 7);
        bf16x8 bv = *(const bf16x8*)(&hl[buf][(d << 6) + (phys << 3)]);
        acc0 = __builtin_amdgcn_mfma_f32_16x16x32_bf16(af, bv, acc0, 0, 0, 0);
      }
      {
        int d = nd0 + 16 + m16;
        int phys = ((ks << 2) + q16) ^ (d & 7);
        bf16x8 bv = *(const bf16x8*)(&hl[buf][(d << 6) + (phys << 3)]);
        acc1 = __builtin_amdgcn_mfma_f32_16x16x32_bf16(af, bv, acc1, 0, 0, 0);
      }
    }
  }

#pragma unroll
  for (int nb = 0; nb < 2; ++nb) {
    f32x4 a = nb ? acc1 : acc0;
    int d = nd0 + (nb << 4) + m16;
#pragma unroll
    for (int r = 0; r < 4; ++r) {
      int irow = i0 + iw + (q16 << 2) + r;
      __builtin_nontemporal_store(a[r], out + ((size_t)(b * Nn + irow) << 7) + d);
    }
  }
}

extern "C" void kernel_launch(void* const* d_in, const int* in_sizes, int n_in,
                              void* d_out, int out_size, void* d_ws, size_t ws_size,
                              hipStream_t stream) {
  const float* x = (const float*)d_in[0];
  const int* adj = (const int*)d_in[1];
  const float* W = (const float*)d_in[2];
  const float* a_vec = (const float*)d_in[3];

  float* out = (float*)d_out;
  float* alpha = out + (size_t)Bn * Nn * Dn;

  char* ws = (char*)d_ws;
  __bf16* hT = (__bf16*)ws;                               // 4 MiB
  float* s1 = (float*)(ws + (size_t)Bn * Dn * Nn * 2);    // B*N fp32
  float* s2 = s1 + (size_t)Bn * Nn;                       // B*N fp32
  float* invl = s2 + (size_t)Bn * Nn;                     // B*N fp32
  unsigned long long* mask64 = (unsigned long long*)(invl + (size_t)Bn * Nn);  // 512 KiB

  gat_k1<<<512, 256, 0, stream>>>(x, W, a_vec, adj, hT, s1, s2, mask64);
  gat_k2a<<<512, 256, 0, stream>>>((const uint32_t*)mask64, s1, s2, invl);
  gat_k2bc<<<1536, 512, 0, stream>>>((const uint32_t*)mask64, hT, s1, s2, invl, out, alpha);
}

// Round 6
// 214.975 us; speedup vs baseline: 1.0030x; 1.0030x over previous
//
#include <hip/hip_runtime.h>
#include <hip/hip_bf16.h>
#include <cstdint>
#include <cstddef>

constexpr int Bn = 8;
constexpr int Nn = 2048;
constexpr int Dn = 128;

typedef __bf16 bf16x8 __attribute__((ext_vector_type(8)));
typedef float f32x4 __attribute__((ext_vector_type(4)));

#define AS1 __attribute__((address_space(1)))
#define AS3 __attribute__((address_space(3)))

static __device__ __forceinline__ void gl_lds16(const void* g, void* l) {
  __builtin_amdgcn_global_load_lds((AS1 const void*)g, (AS3 void*)l, 16, 0, 0);
}

// -----------------------------------------------------------------------------
// Kernel 1: h = x@W (fp32), s1 = h@a1, s2 = h@a2, hT bf16 [B][D][N].
// Fused: pack adj -> bitmask via __ballot (NT loads).
// 512 blocks x 256 thr; 32 rows/block; thread tile 2 rows x 8 cols.
// -----------------------------------------------------------------------------
__global__ __launch_bounds__(256) void gat_k1(
    const float* __restrict__ x, const float* __restrict__ W,
    const float* __restrict__ a_vec, const int* __restrict__ adj,
    __bf16* __restrict__ hT, float* __restrict__ s1, float* __restrict__ s2,
    unsigned long long* __restrict__ mask64) {
  __shared__ __align__(16) float Wl[64 * 144];
  __shared__ __align__(16) float xL[32 * 132];

  const int t = threadIdx.x;
  const int r0 = blockIdx.x * 32;
  const int b = r0 >> 11;
  const int n0 = r0 & (Nn - 1);
  const int rp = (t >> 4) << 1;
  const int c0 = (t & 15) << 3;
  const int c0p = c0 + ((c0 >> 5) << 2);

  float acc[2][8];
#pragma unroll
  for (int r = 0; r < 2; ++r)
#pragma unroll
    for (int c = 0; c < 8; ++c) acc[r][c] = 0.f;

#pragma unroll
  for (int it = 0; it < 4; ++it) {
    int idx = t + (it << 8);
    int rr = idx >> 5, kc = (idx & 31) << 2;
    *(float4*)(xL + rr * 132 + kc) = *(const float4*)(x + (size_t)(r0 + rr) * Dn + kc);
  }

  for (int ph = 0; ph < 2; ++ph) {
    if (ph) __syncthreads();
#pragma unroll
    for (int it = 0; it < 8; ++it) {
      int idx = t + (it << 8);
      int kk = idx >> 5, c4 = (idx & 31) << 2;
      int dsto = kk * 144 + c4 + ((c4 >> 5) << 2);
      *(float4*)(Wl + dsto) = *(const float4*)(W + (size_t)((ph << 6) + kk) * Dn + c4);
    }
    __syncthreads();
    const float* xrow = xL + rp * 132 + (ph << 6);
#pragma unroll 4
    for (int k = 0; k < 64; ++k) {
      float xa0 = xrow[k];
      float xa1 = xrow[132 + k];
      float4 w0 = *(const float4*)(Wl + k * 144 + c0p);
      float4 w1 = *(const float4*)(Wl + k * 144 + c0p + 4);
      float ws[8] = {w0.x, w0.y, w0.z, w0.w, w1.x, w1.y, w1.z, w1.w};
#pragma unroll
      for (int c = 0; c < 8; ++c) {
        acc[0][c] = fmaf(xa0, ws[c], acc[0][c]);
        acc[1][c] = fmaf(xa1, ws[c], acc[1][c]);
      }
    }
  }

  float q1[2] = {0.f, 0.f}, q2[2] = {0.f, 0.f};
#pragma unroll
  for (int c = 0; c < 8; ++c) {
    float a1c = a_vec[c0 + c];
    float a2c = a_vec[Dn + c0 + c];
    q1[0] = fmaf(acc[0][c], a1c, q1[0]);
    q1[1] = fmaf(acc[1][c], a1c, q1[1]);
    q2[0] = fmaf(acc[0][c], a2c, q2[0]);
    q2[1] = fmaf(acc[1][c], a2c, q2[1]);
  }
#pragma unroll
  for (int d = 1; d < 16; d <<= 1) {
    q1[0] += __shfl_xor(q1[0], d);
    q1[1] += __shfl_xor(q1[1], d);
    q2[0] += __shfl_xor(q2[0], d);
    q2[1] += __shfl_xor(q2[1], d);
  }
  if ((t & 15) == 0) {
    s1[b * Nn + n0 + rp] = q1[0];
    s1[b * Nn + n0 + rp + 1] = q1[1];
    s2[b * Nn + n0 + rp] = q2[0];
    s2[b * Nn + n0 + rp + 1] = q2[1];
  }

#pragma unroll
  for (int c = 0; c < 8; ++c) {
    union { __bf16 h[2]; uint32_t u; } pk;
    pk.h[0] = (__bf16)acc[0][c];
    pk.h[1] = (__bf16)acc[1][c];
    *(uint32_t*)(hT + (size_t)(b * Dn + c0 + c) * Nn + n0 + rp) = pk.u;
  }

  // fused adj pack: this block covers ints [blockIdx*8192, +8192)
  {
    const size_t base = (size_t)blockIdx.x * 8192;
#pragma unroll 4
    for (int it = 0; it < 32; ++it) {
      size_t g = base + (it << 8) + t;
      int v = __builtin_nontemporal_load(adj + g);
      unsigned long long bal = __ballot(v > 0);
      if ((t & 63) == 0) mask64[g >> 6] = bal;
    }
  }
}

// -----------------------------------------------------------------------------
// Kernel 2: fused denom + alpha + out-GEMM. 256 blocks x 512 thr.
// Block: (b = blockIdx&7, 64 i-rows). Separable exp: no transcendentals in
// inner loops. NT stores for alpha/out (keep hT L2-resident).
// Wave w: i-tile (w&3)*16, d-half (w>>2)*64.
// -----------------------------------------------------------------------------
__global__ __launch_bounds__(512) void gat_k2b(
    const uint32_t* __restrict__ mask, const __bf16* __restrict__ hT,
    const float* __restrict__ s1, const float* __restrict__ s2,
    float* __restrict__ out, float* __restrict__ alpha) {
  __shared__ __align__(16) float Qs[Nn];            // 8 KB  exp(sj)
  __shared__ __align__(16) float Ss[Nn];            // 8 KB  exp(0.2*sj)
  __shared__ float ivl[64];
  __shared__ __align__(16) __bf16 Pl[2][64 * 72];   // 18 KB
  __shared__ __align__(16) __bf16 hl[2][128 * 64];  // 32 KB, swizzled

  const int t = threadIdx.x;
  const int b = blockIdx.x & 7;
  const int i0 = (blockIdx.x >> 3) << 6;
  const int w = t >> 6, lane = t & 63;
  const int lrow = lane >> 3, ccs = lane & 7;
  const __bf16* __restrict__ hTb = hT + (size_t)b * Dn * Nn;

  // prefetch j-tile 0 into hl[0] (covered by qs-build + pass1)
#pragma unroll
  for (int inst = 0; inst < 2; ++inst) {
    gl_lds16(hTb + (size_t)((w << 4) + (inst << 3) + lrow) * Nn + ((ccs ^ lrow) << 3),
             &hl[0][((w << 4) + (inst << 3)) << 6]);
  }

  // build Q/S tables (the only exps over j)
  {
    float4 sv = *(const float4*)(s2 + b * Nn + (t << 2));
    float4 q, s;
    q.x = __expf(sv.x); q.y = __expf(sv.y); q.z = __expf(sv.z); q.w = __expf(sv.w);
    s.x = __expf(0.2f * sv.x); s.y = __expf(0.2f * sv.y);
    s.z = __expf(0.2f * sv.z); s.w = __expf(0.2f * sv.w);
    *(float4*)(Qs + (t << 2)) = q;
    *(float4*)(Ss + (t << 2)) = s;
  }
  const int ii = t >> 3, sub = t & 7;
  const float si = s1[b * Nn + i0 + ii];
  const float Ei = __expf(si);
  const float Gi = __expf(0.2f * si);
  const float Ti = __expf(-si);  // Qj >= Ti  <=>  si+sj >= 0
  __syncthreads();

  // pass 1: denominator (exp-free)
  const uint32_t* __restrict__ mrow = mask + ((size_t)(i0 + ii) << 6);
  float Aq = 0.f, Bs = 0.f;
  for (int cc = 0; cc < 64; ++cc) {
    uint32_t mw = mrow[cc] >> (sub << 2);
    int j = (cc << 5) + (sub << 2);
    float4 qv = *(const float4*)(Qs + j);
    float4 sv = *(const float4*)(Ss + j);
    float qa[4] = {qv.x, qv.y, qv.z, qv.w};
    float sa[4] = {sv.x, sv.y, sv.z, sv.w};
#pragma unroll
    for (int k = 0; k < 4; ++k) {
      bool on = (mw >> k) & 1u;
      bool ge = qa[k] >= Ti;
      Aq += (on && ge) ? qa[k] : 0.f;
      Bs += (on && !ge) ? sa[k] : 0.f;
    }
  }
  Aq += __shfl_xor(Aq, 1); Bs += __shfl_xor(Bs, 1);
  Aq += __shfl_xor(Aq, 2); Bs += __shfl_xor(Bs, 2);
  Aq += __shfl_xor(Aq, 4); Bs += __shfl_xor(Bs, 4);
  if (sub == 0) ivl[ii] = 1.f / (Ei * Aq + Gi * Bs);
  __syncthreads();
  const float il = ivl[ii];
  const float Pi = Ei * il, Ri = Gi * il;

  const int iw16 = (w & 3) << 4;
  const int dh = (w >> 2) << 6;
  const int q16 = lane >> 4, m16 = lane & 15;
  f32x4 acc[4];
#pragma unroll
  for (int nb = 0; nb < 4; ++nb) acc[nb] = (f32x4){0.f, 0.f, 0.f, 0.f};
  float* __restrict__ arow = alpha + ((size_t)(b * Nn + i0 + ii) << 11);

  for (int jt = 0; jt < 32; ++jt) {
    const int buf = jt & 1;
    const int j0 = jt << 6;
    // alpha for my 8 j's (exp-free): NT to global, bf16 to Pl[buf]
    {
      int j = j0 + (sub << 3);
      uint32_t m8 = (mrow[(jt << 1) + (sub >> 2)] >> ((sub & 3) << 3)) & 0xffu;
      float4 q0 = *(const float4*)(Qs + j);
      float4 q1 = *(const float4*)(Qs + j + 4);
      float4 s0 = *(const float4*)(Ss + j);
      float4 s1v = *(const float4*)(Ss + j + 4);
      float qa[8] = {q0.x, q0.y, q0.z, q0.w, q1.x, q1.y, q1.z, q1.w};
      float sa[8] = {s0.x, s0.y, s0.z, s0.w, s1v.x, s1v.y, s1v.z, s1v.w};
      float av[8];
#pragma unroll
      for (int k = 0; k < 8; ++k) {
        bool ge = qa[k] >= Ti;
        float val = (ge ? Pi : Ri) * (ge ? qa[k] : sa[k]);
        av[k] = ((m8 >> k) & 1u) ? val : 0.f;
      }
      f32x4 o0 = {av[0], av[1], av[2], av[3]};
      f32x4 o1 = {av[4], av[5], av[6], av[7]};
      __builtin_nontemporal_store(o0, (f32x4*)(arow + j));
      __builtin_nontemporal_store(o1, (f32x4*)(arow + j + 4));
      union { __bf16 h[8]; uint4 u; } pk;
#pragma unroll
      for (int k = 0; k < 8; ++k) pk.h[k] = (__bf16)av[k];
      *(uint4*)(&Pl[buf][ii * 72 + (sub << 3)]) = pk.u;
    }
    __syncthreads();  // hl[buf] DMA drained; Pl[buf] visible; prev MFMA done
    if (jt < 31) {
      int jn = j0 + 64;
#pragma unroll
      for (int inst = 0; inst < 2; ++inst) {
        gl_lds16(hTb + (size_t)((w << 4) + (inst << 3) + lrow) * Nn + jn + ((ccs ^ lrow) << 3),
                 &hl[buf ^ 1][((w << 4) + (inst << 3)) << 6]);
      }
    }
#pragma unroll
    for (int ks = 0; ks < 2; ++ks) {
      bf16x8 af = *(const bf16x8*)(&Pl[buf][(iw16 + m16) * 72 + (ks << 5) + (q16 << 3)]);
#pragma unroll
      for (int nb = 0; nb < 4; ++nb) {
        int d = dh + (nb << 4) + m16;
        int phys = ((ks << 2) + q16) ^ (d & 7);
        bf16x8 bv = *(const bf16x8*)(&hl[buf][(d << 6) + (phys << 3)]);
        acc[nb] = __builtin_amdgcn_mfma_f32_16x16x32_bf16(af, bv, acc[nb], 0, 0, 0);
      }
    }
  }

  // epilogue: D[row=(lane>>4)*4+r][col=lane&15]; row->i, col->d; NT stores
#pragma unroll
  for (int nb = 0; nb < 4; ++nb) {
    int d = dh + (nb << 4) + m16;
#pragma unroll
    for (int r = 0; r < 4; ++r) {
      int irow = i0 + iw16 + (q16 << 2) + r;
      __builtin_nontemporal_store(acc[nb][r], out + ((size_t)(b * Nn + irow) << 7) + d);
    }
  }
}

extern "C" void kernel_launch(void* const* d_in, const int* in_sizes, int n_in,
                              void* d_out, int out_size, void* d_ws, size_t ws_size,
                              hipStream_t stream) {
  const float* x = (const float*)d_in[0];
  const int* adj = (const int*)d_in[1];
  const float* W = (const float*)d_in[2];
  const float* a_vec = (const float*)d_in[3];

  float* out = (float*)d_out;
  float* alpha = out + (size_t)Bn * Nn * Dn;

  char* ws = (char*)d_ws;
  __bf16* hT = (__bf16*)ws;                               // 4 MiB
  float* s1 = (float*)(ws + (size_t)Bn * Dn * Nn * 2);    // B*N fp32
  float* s2 = s1 + (size_t)Bn * Nn;                       // B*N fp32
  unsigned long long* mask64 = (unsigned long long*)(s2 + (size_t)Bn * Nn);  // 512 KiB

  gat_k1<<<512, 256, 0, stream>>>(x, W, a_vec, adj, hT, s1, s2, mask64);
  gat_k2b<<<256, 512, 0, stream>>>((const uint32_t*)mask64, hT, s1, s2, out, alpha);
}